// Round 1
// baseline (374.576 us; speedup 1.0000x reference)
//
#include <hip/hip_runtime.h>

#define B_ 32
#define C_ 128
#define H_ 56
#define W_ 56
#define HW_ (H_*W_)            // 3136
#define SIZE_ (C_*HW_)         // 401408
#define HP_ 58
#define WP_ 58
#define PLANE_ (HP_*WP_*C_)    // 430592 elements per batch (bf16)
#define K_ 1152                // 9 * 128
#define EPS_ 1e-5f
#define SLOPE_ 0.1f

typedef __bf16 bf16x8 __attribute__((ext_vector_type(8)));
typedef float  f32x4  __attribute__((ext_vector_type(4)));

__device__ __forceinline__ ushort f2bf(float x) {
    union { float f; unsigned u; } v; v.f = x;
    unsigned r = (v.u + 0x7FFFu + ((v.u >> 16) & 1u)) >> 16;   // RNE
    return (ushort)r;
}

// ---------------------------------------------------------------------------
// prep: conv_w [co][ci][3][3] fp32 -> wA bf16 [co][k], k=(kh*3+kw)*128+ci
//       + fold conv bias + BN2 into per-co scale/shift
// ---------------------------------------------------------------------------
__global__ __launch_bounds__(256) void prep_kernel(
    const float* __restrict__ conv_w, const float* __restrict__ conv_b,
    const float* __restrict__ g2, const float* __restrict__ b2,
    const float* __restrict__ m2, const float* __restrict__ v2,
    ushort* __restrict__ wA, float* __restrict__ scale2, float* __restrict__ shift2)
{
    int tid = blockIdx.x * 256 + threadIdx.x;
    if (tid < C_ * K_) {
        int co = tid / K_;
        int k  = tid - co * K_;
        int khkw = k >> 7, ci = k & 127;
        int kh = khkw / 3, kw = khkw - 3 * kh;
        wA[tid] = f2bf(conv_w[((co * C_ + ci) * 3 + kh) * 3 + kw]);
    }
    if (tid < C_) {
        float sc = g2[tid] * rsqrtf(v2[tid] + EPS_);
        scale2[tid] = sc;
        shift2[tid] = (conv_b[tid] - m2[tid]) * sc + b2[tid];
    }
}

// ---------------------------------------------------------------------------
// zfuse: z = leaky(BN1(cfc_w0*a + cfc_w1*m)) -> bf16, NHWC, zero-padded 58x58
// one block per (b, padded row hp). LDS transpose: read c-major, write c-inner.
// ---------------------------------------------------------------------------
__global__ __launch_bounds__(256) void zfuse_kernel(
    const float* __restrict__ ax, const float* __restrict__ mx,
    const float2* __restrict__ cfc, const float* __restrict__ g1,
    const float* __restrict__ b1, const float* __restrict__ mu1,
    const float* __restrict__ v1, ushort* __restrict__ zp)
{
    __shared__ ushort tile[W_ * 129];   // +1 pad on c-dim stride to kill bank conflicts
    int hp = blockIdx.x, b = blockIdx.y;
    int tid = threadIdx.x;
    ushort* row = zp + (size_t)b * PLANE_ + (size_t)hp * (WP_ * C_);
    if (hp == 0 || hp == HP_ - 1) {           // full zero border rows
        for (int i = tid; i < WP_ * C_; i += 256) row[i] = 0;
        return;
    }
    int h = hp - 1;
    for (int i = tid; i < C_ * W_; i += 256) {
        int c = i / W_;
        int w = i - c * W_;
        int s = c * HW_ + h * W_ + w;
        int gi = b * SIZE_ + s;
        float2 wt = cfc[s];
        float z = wt.x * ax[gi] + wt.y * mx[gi];
        float sc = g1[s] * rsqrtf(v1[s] + EPS_);
        z = (z - mu1[s]) * sc + b1[s];
        z = z > 0.f ? z : SLOPE_ * z;
        tile[w * 129 + c] = f2bf(z);
    }
    __syncthreads();
    if (tid < C_) {                           // zero left/right border columns
        row[tid] = 0;
        row[(WP_ - 1) * C_ + tid] = 0;
    }
    for (int i = tid; i < C_ * W_; i += 256) {
        int w = i >> 7;
        int c = i & 127;
        row[(w + 1) * C_ + c] = tile[w * 129 + c];
    }
}

// ---------------------------------------------------------------------------
// conv: implicit GEMM, M=co(128) x N=pixels x K=1152, bf16 MFMA 16x16x32.
// Block: 4 waves, 64 pixels, all 128 co. Wave: 2 co-tiles x 4 px-tiles.
// Epilogue fuses scale2/shift2 + leaky, writes NCHW fp32.
// ---------------------------------------------------------------------------
__global__ __launch_bounds__(256) void conv_kernel(
    const ushort* __restrict__ zp, const ushort* __restrict__ wA,
    const float* __restrict__ scale2, const float* __restrict__ shift2,
    float* __restrict__ out)
{
    int b = blockIdx.y;
    int px_base = blockIdx.x * 64;
    int wave = threadIdx.x >> 6;
    int lane = threadIdx.x & 63;
    int l16 = lane & 15, quad = lane >> 4;
    int co0 = wave * 32;

    const ushort* zb = zp + (size_t)b * PLANE_ + quad * 8;
    const ushort* pz[4];
    int px[4];
    #pragma unroll
    for (int nt = 0; nt < 4; ++nt) {
        int p = px_base + nt * 16 + l16;
        int h = p / W_;
        int w = p - h * W_;
        px[nt] = p;
        pz[nt] = zb + (h * WP_ + w) * C_;      // top-left tap; (kh,kw) adds uniform offset
    }
    const ushort* pa0 = wA + (co0 + l16) * K_ + quad * 8;
    const ushort* pa1 = pa0 + 16 * K_;

    f32x4 acc[2][4] = {};
    for (int khkw = 0; khkw < 9; ++khkw) {
        int kh = khkw / 3;
        int kw = khkw - 3 * kh;
        int off_pix = (kh * WP_ + kw) * C_;    // wave-uniform per K-group
        int kb = khkw * C_;
        #pragma unroll
        for (int cc = 0; cc < 4; ++cc) {
            int kk = kb + cc * 32;
            bf16x8 a0 = *(const bf16x8*)(pa0 + kk);
            bf16x8 a1 = *(const bf16x8*)(pa1 + kk);
            #pragma unroll
            for (int nt = 0; nt < 4; ++nt) {
                bf16x8 bb = *(const bf16x8*)(pz[nt] + off_pix + cc * 32);
                acc[0][nt] = __builtin_amdgcn_mfma_f32_16x16x32_bf16(a0, bb, acc[0][nt], 0, 0, 0);
                acc[1][nt] = __builtin_amdgcn_mfma_f32_16x16x32_bf16(a1, bb, acc[1][nt], 0, 0, 0);
            }
        }
    }

    #pragma unroll
    for (int t = 0; t < 2; ++t) {
        #pragma unroll
        for (int r = 0; r < 4; ++r) {
            int co = co0 + t * 16 + quad * 4 + r;
            float sc = scale2[co], sh = shift2[co];
            #pragma unroll
            for (int nt = 0; nt < 4; ++nt) {
                float v = acc[t][nt][r] * sc + sh;
                v = v > 0.f ? v : SLOPE_ * v;
                out[(size_t)b * SIZE_ + (size_t)co * HW_ + px[nt]] = v;
            }
        }
    }
}

// ---------------------------------------------------------------------------
extern "C" void kernel_launch(void* const* d_in, const int* in_sizes, int n_in,
                              void* d_out, int out_size, void* d_ws, size_t ws_size,
                              hipStream_t stream) {
    const float* ax     = (const float*)d_in[0];
    const float* mx     = (const float*)d_in[1];
    const float* cfc    = (const float*)d_in[2];
    const float* bn_g   = (const float*)d_in[3];
    const float* bn_b   = (const float*)d_in[4];
    const float* bn_m   = (const float*)d_in[5];
    const float* bn_v   = (const float*)d_in[6];
    const float* conv_w = (const float*)d_in[7];
    const float* conv_b = (const float*)d_in[8];
    const float* g2     = (const float*)d_in[9];
    const float* b2     = (const float*)d_in[10];
    const float* m2     = (const float*)d_in[11];
    const float* v2     = (const float*)d_in[12];
    float* out = (float*)d_out;

    char* ws = (char*)d_ws;
    // zp: 32*58*58*128 bf16 = 27,557,888 B ; wA: 128*1152*2 = 294,912 B ; +2*512 B
    ushort* zp     = (ushort*)ws;
    ushort* wA     = (ushort*)(ws + 27557888);
    float*  scale2 = (float*)(ws + 27852800);
    float*  shift2 = (float*)(ws + 27853312);

    prep_kernel<<<dim3(576), 256, 0, stream>>>(conv_w, conv_b, g2, b2, m2, v2,
                                               wA, scale2, shift2);
    zfuse_kernel<<<dim3(HP_, B_), 256, 0, stream>>>(ax, mx, (const float2*)cfc,
                                                    bn_g, bn_b, bn_m, bn_v, zp);
    conv_kernel<<<dim3(HW_ / 64, B_), 256, 0, stream>>>(zp, wA, scale2, shift2, out);
}

// Round 2
// 236.519 us; speedup vs baseline: 1.5837x; 1.5837x over previous
//
#include <hip/hip_runtime.h>

#define B_ 32
#define C_ 128
#define H_ 56
#define W_ 56
#define HW_ (H_*W_)            // 3136
#define SIZE_ (C_*HW_)         // 401408
#define NPIX_ (B_*HW_)         // 100352 = 784 * 128
#define HP_ 58
#define WP_ 58
#define PLANE_ (HP_*WP_*C_)    // 430592 bf16 elements per batch plane
#define K_ 1152                // 9 * 128
#define EPS_ 1e-5f
#define SLOPE_ 0.1f

typedef __bf16 bf16x8 __attribute__((ext_vector_type(8)));
typedef float  f32x4  __attribute__((ext_vector_type(4)));

__device__ __forceinline__ ushort f2bf(float x) {
    union { float f; unsigned u; } v; v.f = x;
    return (ushort)((v.u + 0x7FFFu + ((v.u >> 16) & 1u)) >> 16);   // RNE
}
__device__ __forceinline__ float lrelu(float z) { return z > 0.f ? z : SLOPE_ * z; }

// async global->LDS, 16B per lane; LDS dest = wave-uniform base + lane*16
__device__ __forceinline__ void glds16(const ushort* g, ushort* l) {
    __builtin_amdgcn_global_load_lds(
        (const __attribute__((address_space(1))) unsigned int*)g,
        (__attribute__((address_space(3))) unsigned int*)l, 16, 0, 0);
}

// ---------------------------------------------------------------------------
// prep: repack conv_w -> bf16 wA[co][k], k=(kh*3+kw)*128+ci; fold bias+BN2;
//       fold BN1 into per-position mix params p0,p1,p2.
// ---------------------------------------------------------------------------
__global__ __launch_bounds__(256) void prep_kernel(
    const float* __restrict__ conv_w, const float* __restrict__ conv_b,
    const float* __restrict__ g2, const float* __restrict__ b2,
    const float* __restrict__ m2, const float* __restrict__ v2,
    const float2* __restrict__ cfc, const float* __restrict__ g1,
    const float* __restrict__ b1, const float* __restrict__ mu1,
    const float* __restrict__ v1,
    ushort* __restrict__ wA, float* __restrict__ scale2, float* __restrict__ shift2,
    float* __restrict__ p0, float* __restrict__ p1, float* __restrict__ p2)
{
    int tid = blockIdx.x * 256 + threadIdx.x;
    if (tid < C_ * K_) {
        int co = tid / K_;
        int k  = tid - co * K_;
        int khkw = k >> 7, ci = k & 127;
        int kh = khkw / 3, kw = khkw - 3 * kh;
        wA[tid] = f2bf(conv_w[((co * C_ + ci) * 3 + kh) * 3 + kw]);
    }
    if (tid < C_) {
        float sc = g2[tid] * rsqrtf(v2[tid] + EPS_);
        scale2[tid] = sc;
        shift2[tid] = (conv_b[tid] - m2[tid]) * sc + b2[tid];
    }
    if (tid < SIZE_) {
        float sc = g1[tid] * rsqrtf(v1[tid] + EPS_);
        float2 wv = cfc[tid];
        p0[tid] = wv.x * sc;
        p1[tid] = wv.y * sc;
        p2[tid] = b1[tid] - mu1[tid] * sc;
    }
}

// ---------------------------------------------------------------------------
// zfuse: z = leaky(a*p0 + m*p1 + p2) -> bf16 NHWC zero-padded [32][58][58][128]
// one block per (b, padded row). float4 loads, LDS transpose (stride 132),
// uint2 coalesced write-out.
// ---------------------------------------------------------------------------
__global__ __launch_bounds__(256) void zfuse_kernel(
    const float4* __restrict__ ax, const float4* __restrict__ mx,
    const float4* __restrict__ p0, const float4* __restrict__ p1,
    const float4* __restrict__ p2, ushort* __restrict__ zp)
{
    __shared__ ushort tile[W_ * 132];   // stride 132: 8B-aligned rows, no 2^k banking
    const int hp = blockIdx.x, b = blockIdx.y;
    const int tid = threadIdx.x;
    ushort* row = zp + (size_t)b * PLANE_ + (size_t)hp * (WP_ * C_);
    if (hp == 0 || hp == HP_ - 1) {            // full zero border rows
        uint2* r2 = (uint2*)row;
        for (int i = tid; i < WP_ * C_ / 4; i += 256) r2[i] = make_uint2(0u, 0u);
        return;
    }
    const int h = hp - 1;
    const int base4 = (b * SIZE_) >> 2;
    for (int i = tid; i < 1792; i += 256) {    // 128 c * 14 float4-groups
        int c  = i / 14;
        int w4 = i - c * 14;
        int s4 = c * (HW_ / 4) + h * (W_ / 4) + w4;   // float4 index into [SIZE_]
        float4 a = ax[base4 + s4];
        float4 m = mx[base4 + s4];
        float4 q0 = p0[s4], q1 = p1[s4], q2 = p2[s4];
        int wb = w4 * 4;
        tile[(wb + 0) * 132 + c] = f2bf(lrelu(a.x * q0.x + m.x * q1.x + q2.x));
        tile[(wb + 1) * 132 + c] = f2bf(lrelu(a.y * q0.y + m.y * q1.y + q2.y));
        tile[(wb + 2) * 132 + c] = f2bf(lrelu(a.z * q0.z + m.z * q1.z + q2.z));
        tile[(wb + 3) * 132 + c] = f2bf(lrelu(a.w * q0.w + m.w * q1.w + q2.w));
    }
    __syncthreads();
    if (tid < C_) {                            // left/right border columns
        row[tid] = 0;
        row[(WP_ - 1) * C_ + tid] = 0;
    }
    for (int j = tid; j < 1792; j += 256) {    // 56 w * 32 uint2-chunks
        int w = j >> 5, cc = j & 31;
        *(uint2*)(row + C_ + w * C_ + cc * 4) = *(const uint2*)(tile + w * 132 + cc * 4);
    }
}

// ---------------------------------------------------------------------------
// conv: implicit GEMM, M=128co x N=100352px x K=1152, bf16 MFMA 16x16x32.
// m97 structure: 128x128 tile, BK=32, 16KB single-buffer LDS, global_load_lds.
// Pixel tiles span the global (b,h,w) space: 784 blocks, no tail.
// ---------------------------------------------------------------------------
__global__ __launch_bounds__(256) void conv_kernel(
    const ushort* __restrict__ zp, const ushort* __restrict__ wA,
    const float* __restrict__ scale2, const float* __restrict__ shift2,
    float* __restrict__ out)
{
    __shared__ ushort As[128 * 32];   // 8 KB: As[co][32]  rows of 64B
    __shared__ ushort Bs[128 * 32];   // 8 KB: Bs[px][32]

    const int tid  = threadIdx.x;
    const int wave = tid >> 6, lane = tid & 63;
    const int l16  = lane & 15, quad = lane >> 4;
    const int pbase = blockIdx.x * 128;

    // ---- staging roles: each wave stages 32 rows (2 glds of 16 rows) ----
    const int srow = wave * 32 + (lane >> 2);     // row for instr 0 (+16 for instr 1)
    const int sch  = lane & 3;                    // 16B chunk within 64B row
    const ushort* agA = wA + srow * K_ + sch * 8; // A: weights, +16*K_ for instr 1

    int pf0 = pbase + srow;
    int bb0 = pf0 / HW_, pi0 = pf0 - bb0 * HW_;
    int h0 = pi0 / W_, w0 = pi0 - h0 * W_;
    const ushort* bgB0 = zp + (size_t)bb0 * PLANE_ + (h0 * WP_ + w0) * C_ + sch * 8;
    int pf1 = pf0 + 16;
    int bb1 = pf1 / HW_, pi1 = pf1 - bb1 * HW_;
    int h1 = pi1 / W_, w1 = pi1 - h1 * W_;
    const ushort* bgB1 = zp + (size_t)bb1 * PLANE_ + (h1 * WP_ + w1) * C_ + sch * 8;

    ushort* lA0 = As + (wave * 32) * 32;          // wave-uniform LDS dests
    ushort* lA1 = As + (wave * 32 + 16) * 32;
    ushort* lB0 = Bs + (wave * 32) * 32;
    ushort* lB1 = Bs + (wave * 32 + 16) * 32;

    // ---- compute roles: wave = 64co x 64px quadrant ----
    const int cob = (wave & 1) * 64;
    const int pxb = (wave >> 1) * 64;

    f32x4 acc[4][4] = {};

    for (int tap = 0; tap < 9; ++tap) {
        const int kh = tap / 3, kw = tap - kh * 3;
        const int zoff = (kh * WP_ + kw) * C_;    // wave-uniform tap offset in zp
        const int aoff = tap * C_;                // k-offset in wA
        #pragma unroll
        for (int ks = 0; ks < 4; ++ks) {
            const int ko = ks * 32;
            __syncthreads();                      // protect LDS from prev iter readers
            glds16(agA + aoff + ko,            lA0);
            glds16(agA + 16 * K_ + aoff + ko,  lA1);
            glds16(bgB0 + zoff + ko,           lB0);
            glds16(bgB1 + zoff + ko,           lB1);
            __syncthreads();                      // drains vmcnt: staging visible
            bf16x8 af[4], bfr[4];
            #pragma unroll
            for (int mt = 0; mt < 4; ++mt)
                af[mt] = *(const bf16x8*)(As + (cob + mt * 16 + l16) * 32 + quad * 8);
            #pragma unroll
            for (int nt = 0; nt < 4; ++nt)
                bfr[nt] = *(const bf16x8*)(Bs + (pxb + nt * 16 + l16) * 32 + quad * 8);
            #pragma unroll
            for (int mt = 0; mt < 4; ++mt)
                #pragma unroll
                for (int nt = 0; nt < 4; ++nt)
                    acc[mt][nt] = __builtin_amdgcn_mfma_f32_16x16x32_bf16(
                        af[mt], bfr[nt], acc[mt][nt], 0, 0, 0);
        }
    }

    // ---- epilogue: fused scale/shift + leaky, NCHW fp32 stores ----
    int pob[4];
    #pragma unroll
    for (int nt = 0; nt < 4; ++nt) {
        int pf = pbase + pxb + nt * 16 + l16;
        int bb = pf / HW_;
        pob[nt] = bb * SIZE_ + (pf - bb * HW_);
    }
    #pragma unroll
    for (int mt = 0; mt < 4; ++mt) {
        #pragma unroll
        for (int r = 0; r < 4; ++r) {
            int co = cob + mt * 16 + quad * 4 + r;
            float sc = scale2[co], sh = shift2[co];
            #pragma unroll
            for (int nt = 0; nt < 4; ++nt) {
                float v = acc[mt][nt][r] * sc + sh;
                out[(size_t)pob[nt] + co * HW_] = lrelu(v);
            }
        }
    }
}

// ---------------------------------------------------------------------------
extern "C" void kernel_launch(void* const* d_in, const int* in_sizes, int n_in,
                              void* d_out, int out_size, void* d_ws, size_t ws_size,
                              hipStream_t stream) {
    const float* ax     = (const float*)d_in[0];
    const float* mx     = (const float*)d_in[1];
    const float* cfc    = (const float*)d_in[2];
    const float* bn_g   = (const float*)d_in[3];
    const float* bn_b   = (const float*)d_in[4];
    const float* bn_m   = (const float*)d_in[5];
    const float* bn_v   = (const float*)d_in[6];
    const float* conv_w = (const float*)d_in[7];
    const float* conv_b = (const float*)d_in[8];
    const float* g2     = (const float*)d_in[9];
    const float* b2     = (const float*)d_in[10];
    const float* m2     = (const float*)d_in[11];
    const float* v2     = (const float*)d_in[12];
    float* out = (float*)d_out;

    char* ws = (char*)d_ws;
    // zp: 27,557,888 B | wA: 294,912 B | scale2/shift2: 512 B each | p0/p1/p2: 1,605,632 B each
    ushort* zp     = (ushort*)ws;
    ushort* wA     = (ushort*)(ws + 27557888);
    float*  scale2 = (float*)(ws + 27852800);
    float*  shift2 = (float*)(ws + 27853312);
    float*  p0     = (float*)(ws + 27853824);
    float*  p1     = (float*)(ws + 29459456);
    float*  p2     = (float*)(ws + 31065088);

    prep_kernel<<<dim3((SIZE_ + 255) / 256), 256, 0, stream>>>(
        conv_w, conv_b, g2, b2, m2, v2, (const float2*)cfc,
        bn_g, bn_b, bn_m, bn_v, wA, scale2, shift2, p0, p1, p2);
    zfuse_kernel<<<dim3(HP_, B_), 256, 0, stream>>>(
        (const float4*)ax, (const float4*)mx,
        (const float4*)p0, (const float4*)p1, (const float4*)p2, zp);
    conv_kernel<<<dim3(NPIX_ / 128), 256, 0, stream>>>(zp, wA, scale2, shift2, out);
}